// Round 2
// baseline (816.678 us; speedup 1.0000x reference)
//
#include <hip/hip_runtime.h>
#include <cmath>

// ---------------- problem constants ----------------
#define E_    8
#define H_    2048
#define IH    1408      // I
#define I2    2816      // 2*I
#define SIH   2816      // SI
#define SI2   5632      // 2*SI
#define KTOP  2
#define T_    4096
#define NA    (T_*KTOP)          // 8192 routed assignments
#define MAXR  (NA + E_*256)      // 10240: expert segments padded to 256

typedef __attribute__((ext_vector_type(4)))  short  short4v;
typedef __attribute__((ext_vector_type(8)))  __bf16 bf16x8;
typedef __attribute__((ext_vector_type(4)))  float  f32x4;
typedef unsigned short bf16r;

__device__ __forceinline__ bf16r f2b(float f) {          // RNE fp32->bf16
    unsigned int u = __float_as_uint(f);
    return (bf16r)((u + 0x7FFFu + ((u >> 16) & 1u)) >> 16);
}
__device__ __forceinline__ float b2f(bf16r s) {
    return __uint_as_float(((unsigned int)s) << 16);
}

// async global->LDS, 16B/lane; LDS dest is wave-uniform base (+lane*16 by HW)
__device__ __forceinline__ void gld16(const bf16r* g, void* l) {
    __builtin_amdgcn_global_load_lds((const __attribute__((address_space(1))) void*)g,
                                     (__attribute__((address_space(3))) void*)l, 16, 0, 0);
}
// raw barrier: no compiler-inserted vmcnt(0) drain
__device__ __forceinline__ void barrier_raw() { asm volatile("s_barrier" ::: "memory"); }
template<int N> __device__ __forceinline__ void vmwait() {
    asm volatile("s_waitcnt vmcnt(%0)" :: "i"(N) : "memory");
}

// ---------------- routing: count/scan/scatter, 256-aligned segments ----------------
// route ints: [32..40]=off [64,64+MAXR)=perm ; wrow float[MAXR] ; pos int[NA]
__global__ void route_k(const int* __restrict__ idx, const float* __restrict__ tw,
                        int* __restrict__ route) {
    __shared__ int cnt[E_], cur[E_], offs[E_ + 1];
    int t = threadIdx.x;
    if (t < E_) { cnt[t] = 0; cur[t] = 0; }
    float* wrow = (float*)(route + 64 + MAXR);
    int* pos = route + 64 + 2 * MAXR;
    for (int i = t; i < MAXR; i += 256) { route[64 + i] = -1; wrow[i] = 0.f; }
    __syncthreads();
    for (int a = t; a < NA; a += 256) atomicAdd(&cnt[idx[a]], 1);
    __syncthreads();
    if (t == 0) {
        int run = 0;
        for (int e = 0; e < E_; e++) { offs[e] = run; run += ((cnt[e] + 255) >> 8) << 8; }
        offs[E_] = run;
    }
    __syncthreads();
    for (int a = t; a < NA; a += 256) {
        int e = idx[a];
        int p = atomicAdd(&cur[e], 1);
        int r = offs[e] + p;
        route[64 + r] = a / KTOP;
        wrow[r] = tw[a];
        pos[a] = r;
    }
    if (t <= E_) route[32 + t] = offs[t];
}

// ---------------- fp32 -> bf16 flat convert (x) ----------------
__global__ void cvt_k(const float* __restrict__ in, bf16r* __restrict__ out, int n4) {
    int i = blockIdx.x * 256 + threadIdx.x;
    if (i < n4) {
        float4 v = ((const float4*)in)[i];
        short4v o;
        o[0] = (short)f2b(v.x); o[1] = (short)f2b(v.y);
        o[2] = (short)f2b(v.z); o[3] = (short)f2b(v.w);
        ((short4v*)out)[i] = o;
    }
}

// ---------------- fp32 [R][C] -> bf16 [C][R] transpose-convert ----------------
__global__ void tconv_k(const float* __restrict__ in, bf16r* __restrict__ out,
                        int R, int C, long ims, long oms) {
    __shared__ bf16r tile[64][65];
    const float* inp = in + blockIdx.z * ims;
    bf16r* outp = out + blockIdx.z * oms;
    int c0 = blockIdx.x * 64, r0 = blockIdx.y * 64;
    int tx = threadIdx.x, ty = threadIdx.y;        // 64 x 4
    #pragma unroll
    for (int j = 0; j < 16; j++) {
        int r = ty * 16 + j;
        tile[r][tx] = f2b(inp[(long)(r0 + r) * C + c0 + tx]);
    }
    __syncthreads();
    #pragma unroll
    for (int j = 0; j < 16; j++) {
        int c = ty * 16 + j;
        outp[(long)(c0 + c) * R + r0 + tx] = tile[tx][c];
    }
}

// ---------------- combine: out[t] += outR[pos[2t]] + outR[pos[2t+1]] ----------------
__global__ void comb_k(float* __restrict__ out, const bf16r* __restrict__ outR,
                       const int* __restrict__ pos) {
    int i = blockIdx.x * 256 + threadIdx.x;        // over T_*H_/4
    int t  = i >> 9;                               // H_/4 = 512
    int c4 = i & 511;
    int p0 = pos[2 * t], p1 = pos[2 * t + 1];
    float4 o = ((float4*)out)[i];
    short4v r0 = ((const short4v*)(outR + (long)p0 * H_))[c4];
    short4v r1 = ((const short4v*)(outR + (long)p1 * H_))[c4];
    o.x += b2f((bf16r)r0[0]) + b2f((bf16r)r1[0]);
    o.y += b2f((bf16r)r0[1]) + b2f((bf16r)r1[1]);
    o.z += b2f((bf16r)r0[2]) + b2f((bf16r)r1[2]);
    o.w += b2f((bf16r)r0[3]) + b2f((bf16r)r1[3]);
    ((float4*)out)[i] = o;
}

// =====================================================================
// 8-phase 256-row GEMM, m201-style phases: ds_read issue BEFORE barrier.
//   BM=256, BK=64, 512 thr (8 waves, 2Mx4N).  BNv=256 (or 128).
//   Quadrants per tile: (0,0),(0,1),(1,0),(1,1). Frag reads one-per-half:
//     p0: read A0,B0   p1: read B1   p2: read A1   p3: none
//   Stage issue (half-tile per phase):
//     p0: B1(t+1)   p1: A1(t+1)   p2: A0(t+2)   p3: B0(t+2)
//   vmwait<VW=4+2*LB> at p0/p1/p3 establishes readiness exactly one phase
//   before each half's frags are read (queue-count induction, see notes).
//   Readiness of reads at issue time is guaranteed by the PREVIOUS phase's
//   vmwait+barrier, so pre-barrier ds_read issue is race-free; WAR on the
//   staged buffers is guarded by the intervening double barriers.
//   LDS swizzle: 16B k-slot u stored at u^(row&7) via pre-swizzled GLOBAL
//   source (linear LDS dest, rule #21), XOR applied on ds_read. (verified)
//   EPI: 0 = paired swiglu bf16 store; 1 = fp32 plain; 2 = bf16 w*acc store.
// =====================================================================

#define PH_READ_A(MH) { _Pragma("unroll") for (int i4 = 0; i4 < 4; i4++) \
                        _Pragma("unroll") for (int kk = 0; kk < 2; kk++) \
                            af[(MH)][i4][kk] = rdA(cur, (MH), i4, kk); }
#define PH_READ_B(NH) { _Pragma("unroll") for (int j2 = 0; j2 < NJ2; j2++) \
                        _Pragma("unroll") for (int kk = 0; kk < 2; kk++) \
                            bfr[(NH)][j2][kk] = rdB(cur, (NH), j2, kk); }
#define PH_MMA(MH, NH) { __builtin_amdgcn_s_setprio(1); \
    _Pragma("unroll") for (int i4 = 0; i4 < 4; i4++) \
    _Pragma("unroll") for (int j2 = 0; j2 < NJ2; j2++) \
    _Pragma("unroll") for (int kk = 0; kk < 2; kk++) \
        acc[(MH)][(NH)][i4][j2] = __builtin_amdgcn_mfma_f32_16x16x32_bf16( \
            af[(MH)][i4][kk], bfr[(NH)][j2][kk], acc[(MH)][(NH)][i4][j2], 0, 0, 0); \
    __builtin_amdgcn_s_setprio(0); }

template<int BNv, int KD, bool GATHER, bool ROUTED, bool PAIRED, int EPI>
__global__ __launch_bounds__(512, 2)
void g8_k(const bf16r* __restrict__ A,
          const bf16r* __restrict__ Bt, long bstride, int F,
          void* __restrict__ Cv, int ldc,
          const int* __restrict__ off, const int* __restrict__ perm,
          const float* __restrict__ wrow, int gM)
{
    constexpr int NJ2 = BNv / 128;           // N frags per wave per quadrant (2 or 1)
    constexpr int LB  = NJ2;                 // gld16 per thread per B half
    constexpr int BHE = BNv * 32;            // B half elements
    constexpr int NT  = KD / 64;
    constexpr int VW  = 4 + 2 * LB;          // steady-state wait count
    static_assert(!PAIRED || NJ2 == 2, "paired swiglu needs BN=256");
    static_assert(NT >= 4 && (NT & 1) == 0, "even K-tile count >= 4");

    extern __shared__ __align__(16) char smem[];
    bf16r* lA = (bf16r*)smem;                // [buf][half] x 8192 elems
    bf16r* lB = (bf16r*)(smem + 65536);

    // bijective XCD-aware remap (m204), then M-fastest (same-B blocks contiguous)
    int nwg = gridDim.x, orig = blockIdx.x;
    int q8 = nwg >> 3, r8 = nwg & 7, xc = orig & 7, o8 = orig >> 3;
    int wgid = (xc < r8 ? xc * (q8 + 1) : r8 * (q8 + 1) + (xc - r8) * q8) + o8;
    int mt = wgid % gM, nt = wgid / gM;
    const int r0 = mt * 256;
    int e = 0;
    if (ROUTED) {
        if (r0 >= off[E_]) return;           // uniform: before any barrier
        while (e + 1 < E_ && off[e + 1] <= r0) e++;
    }
    const bf16r* Bte = ROUTED ? Bt + (long)e * bstride : Bt;

    const int tid  = threadIdx.x;
    const int lane = tid & 63;
    const int wave = tid >> 6;
    const int wm = wave >> 2, wn = wave & 3;
    const int ml = lane & 15, kg = lane >> 4;
    const int srw  = lane >> 3;                       // staged row within 8-row group
    const int ksrc = ((lane & 7) ^ srw) * 8;          // pre-swizzled global k offset

    // ---- staging pointers (k0 added per tile) ----
    const bf16r* pA[2][2];
    #pragma unroll
    for (int h = 0; h < 2; h++)
        #pragma unroll
        for (int l = 0; l < 2; l++) {
            int gr = r0 + h * 128 + (wave + 8 * l) * 8 + srw;
            long rw = gr;
            if (GATHER) { int tk = perm[gr]; rw = (tk < 0) ? 0 : tk; }
            pA[h][l] = A + rw * (long)KD + ksrc;
        }
    const bf16r* pB[2][LB];
    #pragma unroll
    for (int nh = 0; nh < 2; nh++)
        #pragma unroll
        for (int l = 0; l < LB; l++) {
            int lr = (wave + 8 * l) * 8 + srw;        // local B row in half
            long gr;
            if (PAIRED) {
                int wn_ = lr >> 5, j2_ = (lr >> 4) & 1, ml_ = lr & 15;
                gr = (long)(nt * 128 + nh * 64 + wn_ * 16 + ml_) + (j2_ ? (long)F : 0L);
            } else if (NJ2 == 2) gr = (long)(nt * 256 + nh * 128 + lr);
            else                 gr = (long)(nt * 128 + nh * 64  + lr);
            pB[nh][l] = Bte + gr * (long)KD + ksrc;
        }

    auto stgA = [&](int b, int h, int kp) {
        char* d = smem + ((b * 2 + h) << 14) + (wave << 10);
        gld16(pA[h][0] + kp, d);
        gld16(pA[h][1] + kp, d + 8192);
    };
    auto stgB = [&](int b, int nh, int kp) {
        char* d = smem + 65536 + (b * 2 + nh) * (BHE * 2) + (wave << 10);
        gld16(pB[nh][0] + kp, d);
        if constexpr (LB == 2) gld16(pB[nh][1] + kp, d + 8192);
    };
    // swizzled reads: logical 16B k-unit u lives at u^(row&7)
    auto rdA = [&](int b, int mh, int i4, int kk) -> bf16x8 {
        int row = wm * 64 + i4 * 16 + ml;
        int u = kk * 4 + kg;
        int ee = ((b * 2 + mh) << 13) + row * 64 + ((u ^ (row & 7)) << 3);
        return *(const bf16x8*)&lA[ee];
    };
    auto rdB = [&](int b, int nh, int j2, int kk) -> bf16x8 {
        int rb = (NJ2 == 2) ? (wn * 32 + j2 * 16 + ml) : (wn * 16 + ml);
        int u = kk * 4 + kg;
        int ee = (b * 2 + nh) * BHE + rb * 64 + ((u ^ (rb & 7)) << 3);
        return *(const bf16x8*)&lB[ee];
    };

    f32x4 acc[2][2][4][NJ2];
    #pragma unroll
    for (int a0 = 0; a0 < 2; a0++)
        #pragma unroll
        for (int b0 = 0; b0 < 2; b0++)
            #pragma unroll
            for (int i = 0; i < 4; i++)
                #pragma unroll
                for (int j = 0; j < NJ2; j++)
                    acc[a0][b0][i][j] = f32x4{0.f, 0.f, 0.f, 0.f};

    bf16x8 af[2][4][2], bfr[2][NJ2][2];

    // prologue: tile0 all 4 halves + tile1 A0,B0; drain tile0 only
    vmwait<0>();
    stgA(0, 0, 0); stgB(0, 0, 0); stgB(0, 1, 0); stgA(0, 1, 0);
    stgA(1, 0, 64); stgB(1, 0, 64);
    vmwait<LB + 2>(); barrier_raw();

    #pragma unroll 2
    for (int t = 0; t < NT; t++) {
        const int cur = t & 1, nxt = cur ^ 1;
        const int k1 = ((t + 1 < NT) ? (t + 1) : (NT - 1)) * 64;  // clamped: uniform counts
        const int k2 = ((t + 2 < NT) ? (t + 2) : (NT - 1)) * 64;
        // ---- phase 0: quadrant (0,0) ----
        PH_READ_A(0); PH_READ_B(0);     // ready since end of (t-1,p3)
        stgB(nxt, 1, k1);               // B1(t+1)
        vmwait<VW>();                   // completes B1(t)
        barrier_raw();
        PH_MMA(0, 0);
        barrier_raw();
        // ---- phase 1: (0,1) ----
        PH_READ_B(1);                   // B1(t): ready since p0's wait+barrier
        stgA(nxt, 1, k1);               // A1(t+1)
        vmwait<VW>();                   // completes A1(t)
        barrier_raw();
        PH_MMA(0, 1);
        barrier_raw();
        // ---- phase 2: (1,0) ----
        PH_READ_A(1);                   // A1(t): ready since p1's wait+barrier
        stgA(cur, 0, k2);               // A0(t+2) (same-parity buffer)
        barrier_raw();
        PH_MMA(1, 0);
        barrier_raw();
        // ---- phase 3: (1,1) ----
        stgB(cur, 0, k2);               // B0(t+2)
        vmwait<VW>();                   // completes A0(t+1), B0(t+1)
        barrier_raw();
        PH_MMA(1, 1);
        barrier_raw();
    }
    vmwait<0>();                        // drain LDS-DMA before wave exit

    // ---------------- epilogue: D row = kg*4+rr, col = ml (verified m89) ----------------
    const long colbase = (long)nt * (PAIRED ? 128 : BNv);
    #pragma unroll
    for (int mh = 0; mh < 2; mh++)
        #pragma unroll
        for (int i4 = 0; i4 < 4; i4++)
            #pragma unroll
            for (int rr = 0; rr < 4; rr++) {
                long row = (long)r0 + mh * 128 + wm * 64 + i4 * 16 + kg * 4 + rr;
                if constexpr (PAIRED) {
                    bf16r* ap = (bf16r*)Cv + row * (long)ldc + colbase;
                    #pragma unroll
                    for (int nh = 0; nh < 2; nh++) {
                        float g = acc[mh][nh][i4][0][rr];
                        float u = acc[mh][nh][i4][1][rr];
                        float s = g / (1.0f + __expf(-g));
                        ap[nh * 64 + wn * 16 + ml] = f2b(s * u);
                    }
                } else if constexpr (EPI == 1) {
                    float* cp = (float*)Cv + row * (long)ldc + colbase;
                    #pragma unroll
                    for (int nh = 0; nh < 2; nh++)
                        #pragma unroll
                        for (int j2 = 0; j2 < NJ2; j2++)
                            cp[nh * (BNv / 2) + wn * (BNv / 8) + j2 * 16 + ml] =
                                acc[mh][nh][i4][j2][rr];
                } else {  // EPI == 2: bf16 w*acc, row-contiguous (combined later)
                    int tok = perm[row];
                    if (tok >= 0) {
                        float w = wrow[row];
                        bf16r* cp = (bf16r*)Cv + row * (long)ldc + colbase;
                        #pragma unroll
                        for (int nh = 0; nh < 2; nh++)
                            #pragma unroll
                            for (int j2 = 0; j2 < NJ2; j2++)
                                cp[nh * (BNv / 2) + wn * (BNv / 8) + j2 * 16 + ml] =
                                    f2b(w * acc[mh][nh][i4][j2][rr]);
                    }
                }
            }
}

#undef PH_READ_A
#undef PH_READ_B
#undef PH_MMA

// ---------------- launcher ----------------
extern "C" void kernel_launch(void* const* d_in, const int* in_sizes, int n_in,
                              void* d_out, int out_size, void* d_ws, size_t ws_size,
                              hipStream_t stream)
{
    const float* x   = (const float*)d_in[0];
    const float* tw  = (const float*)d_in[1];
    const float* W1  = (const float*)d_in[2];
    const float* W2  = (const float*)d_in[3];
    const float* Ws1 = (const float*)d_in[4];
    const float* Ws2 = (const float*)d_in[5];
    const int*   tix = (const int*)d_in[6];
    float* out = (float*)d_out;

    char* ws    = (char*)d_ws;
    int*  route = (int*)ws;
    const int*   off  = route + 32;
    const int*   perm = route + 64;
    const float* wrow = (const float*)(route + 64 + MAXR);
    const int*   pos  = route + 64 + 2 * MAXR;

    bf16r* xb   = (bf16r*)(ws + (1u << 20));
    bf16r* W1t  = xb   + (size_t)T_ * H_;
    bf16r* W2t  = W1t  + (size_t)E_ * I2 * H_;
    bf16r* Ws1t = W2t  + (size_t)E_ * H_ * IH;
    bf16r* Ws2t = Ws1t + (size_t)SI2 * H_;
    bf16r* actS = Ws2t + (size_t)H_ * SIH;
    bf16r* actR = actS + (size_t)T_ * SIH;      // total ~243 MB
    // outR [MAXR][H] bf16 (40 MB) aliases W1t (92 MB), which is dead after routed GEMM1
    bf16r* outR = W1t;

    static bool attr_done = false;
    if (!attr_done) {
        hipFuncSetAttribute(reinterpret_cast<const void*>(&g8_k<256,2048,false,false,true,0>),
                            hipFuncAttributeMaxDynamicSharedMemorySize, 131072);
        hipFuncSetAttribute(reinterpret_cast<const void*>(&g8_k<256,2048,true,true,true,0>),
                            hipFuncAttributeMaxDynamicSharedMemorySize, 131072);
        hipFuncSetAttribute(reinterpret_cast<const void*>(&g8_k<128,2816,false,false,false,1>),
                            hipFuncAttributeMaxDynamicSharedMemorySize, 98304);
        hipFuncSetAttribute(reinterpret_cast<const void*>(&g8_k<256,1408,false,true,false,2>),
                            hipFuncAttributeMaxDynamicSharedMemorySize, 131072);
        attr_done = true;
    }

    // routing (single block)
    route_k<<<1, 256, 0, stream>>>(tix, tw, route);

    // converts: x flat; weights transpose-convert to [N][K] bf16
    cvt_k<<<(T_ * H_ / 4 + 255) / 256, 256, 0, stream>>>(x, xb, T_ * H_ / 4);
    tconv_k<<<dim3(SI2 / 64, H_ / 64, 1), dim3(64, 4), 0, stream>>>(Ws1, Ws1t, H_, SI2, 0, 0);
    tconv_k<<<dim3(H_ / 64, SIH / 64, 1), dim3(64, 4), 0, stream>>>(Ws2, Ws2t, SIH, H_, 0, 0);
    tconv_k<<<dim3(I2 / 64, H_ / 64, E_), dim3(64, 4), 0, stream>>>(W1, W1t, H_, I2,
                                                                    (long)H_ * I2, (long)I2 * H_);
    tconv_k<<<dim3(H_ / 64, IH / 64, E_), dim3(64, 4), 0, stream>>>(W2, W2t, IH, H_,
                                                                    (long)IH * H_, (long)H_ * IH);

    // shared expert: fused GEMM1+swiglu -> actS [T][SIH]
    g8_k<256,2048,false,false,true,0><<<dim3((SIH/128)*(T_/256)), dim3(512), 131072, stream>>>(
        xb, Ws1t, 0, SIH, actS, SIH, nullptr, nullptr, nullptr, T_/256);
    // shared expert GEMM2 -> out (fp32 plain store)
    g8_k<128,2816,false,false,false,1><<<dim3((H_/128)*(T_/256)), dim3(512), 98304, stream>>>(
        actS, Ws2t, 0, 0, out, H_, nullptr, nullptr, nullptr, T_/256);
    // routed: fused GEMM1+swiglu (gathered rows) -> actR [MAXR][IH]
    g8_k<256,2048,true,true,true,0><<<dim3((IH/128)*(MAXR/256)), dim3(512), 131072, stream>>>(
        xb, W1t, (long)I2 * H_, IH, actR, IH, off, perm, nullptr, MAXR/256);
    // routed GEMM2 -> bf16 w*acc rows into outR (no atomics)
    g8_k<256,1408,false,true,false,2><<<dim3((H_/256)*(MAXR/256)), dim3(512), 131072, stream>>>(
        actR, W2t, (long)H_ * IH, 0, outR, H_, off, perm, wrow, MAXR/256);
    // combine: out[t] += outR[pos0] + outR[pos1]
    comb_k<<<T_ * H_ / 4 / 256, 256, 0, stream>>>(out, outR, pos);
}

// Round 3
// 748.602 us; speedup vs baseline: 1.0909x; 1.0909x over previous
//
#include <hip/hip_runtime.h>
#include <cmath>

// ---------------- problem constants ----------------
#define E_    8
#define H_    2048
#define IH    1408      // I
#define I2    2816      // 2*I
#define SIH   2816      // SI
#define SI2   5632      // 2*SI
#define KTOP  2
#define T_    4096
#define NA    (T_*KTOP)          // 8192 routed assignments
#define MAXR  (NA + E_*256)      // 10240: expert segments padded to 256

// merged-dispatch block counts
#define NS1   ((SIH/128)*(T_/256))    // 352 shared GEMM1 tiles
#define NR1   ((IH/128)*(MAXR/256))   // 440 routed GEMM1 tiles
#define NS2   ((H_/128)*(T_/256))     // 256 shared GEMM2 tiles
#define NR2   ((H_/256)*(MAXR/256))   // 320 routed GEMM2 tiles

typedef __attribute__((ext_vector_type(4)))  short  short4v;
typedef __attribute__((ext_vector_type(8)))  __bf16 bf16x8;
typedef __attribute__((ext_vector_type(4)))  float  f32x4;
typedef unsigned short bf16r;

__device__ __forceinline__ bf16r f2b(float f) {          // RNE fp32->bf16
    unsigned int u = __float_as_uint(f);
    return (bf16r)((u + 0x7FFFu + ((u >> 16) & 1u)) >> 16);
}
__device__ __forceinline__ float b2f(bf16r s) {
    return __uint_as_float(((unsigned int)s) << 16);
}

// async global->LDS, 16B/lane; LDS dest is wave-uniform base (+lane*16 by HW)
__device__ __forceinline__ void gld16(const bf16r* g, void* l) {
    __builtin_amdgcn_global_load_lds((const __attribute__((address_space(1))) void*)g,
                                     (__attribute__((address_space(3))) void*)l, 16, 0, 0);
}
// raw barrier: no compiler-inserted vmcnt(0) drain
__device__ __forceinline__ void barrier_raw() { asm volatile("s_barrier" ::: "memory"); }
template<int N> __device__ __forceinline__ void vmwait() {
    asm volatile("s_waitcnt vmcnt(%0)" :: "i"(N) : "memory");
}

// ---------------- routing: count/scan/scatter, 256-aligned segments ----------------
// route ints: [32..40]=off [64,64+MAXR)=perm ; wrow float[MAXR] ; pos int[NA]
__global__ void route_k(const int* __restrict__ idx, const float* __restrict__ tw,
                        int* __restrict__ route) {
    __shared__ int cnt[E_], cur[E_], offs[E_ + 1];
    int t = threadIdx.x;
    if (t < E_) { cnt[t] = 0; cur[t] = 0; }
    float* wrow = (float*)(route + 64 + MAXR);
    int* pos = route + 64 + 2 * MAXR;
    for (int i = t; i < MAXR; i += 256) { route[64 + i] = -1; wrow[i] = 0.f; }
    __syncthreads();
    for (int a = t; a < NA; a += 256) atomicAdd(&cnt[idx[a]], 1);
    __syncthreads();
    if (t == 0) {
        int run = 0;
        for (int e = 0; e < E_; e++) { offs[e] = run; run += ((cnt[e] + 255) >> 8) << 8; }
        offs[E_] = run;
    }
    __syncthreads();
    for (int a = t; a < NA; a += 256) {
        int e = idx[a];
        int p = atomicAdd(&cur[e], 1);
        int r = offs[e] + p;
        route[64 + r] = a / KTOP;
        wrow[r] = tw[a];
        pos[a] = r;
    }
    if (t <= E_) route[32 + t] = offs[t];
}

// ---------------- fp32 -> bf16 flat convert (x) ----------------
__global__ void cvt_k(const float* __restrict__ in, bf16r* __restrict__ out, int n4) {
    int i = blockIdx.x * 256 + threadIdx.x;
    if (i < n4) {
        float4 v = ((const float4*)in)[i];
        short4v o;
        o[0] = (short)f2b(v.x); o[1] = (short)f2b(v.y);
        o[2] = (short)f2b(v.z); o[3] = (short)f2b(v.w);
        ((short4v*)out)[i] = o;
    }
}

// ---------------- fp32 [R][C] -> bf16 [C][R] transpose-convert, vectorized ----------------
// 512 threads, 64x64 tile. float4 reads (256B/16 lanes), LDS-transposed store,
// b128 LDS reads, 16B global stores (128B/8 lanes).
__global__ void tconv2_k(const float* __restrict__ in, bf16r* __restrict__ out,
                         int R, int C, long ims, long oms) {
    __shared__ bf16r tile[64][72];                 // [c][r], pad 8 to spread banks
    const float* inp = in + blockIdx.z * ims;
    bf16r* outp = out + blockIdx.z * oms;
    int c0 = blockIdx.x * 64, r0 = blockIdx.y * 64;
    int t = threadIdx.x;
    int tc4 = (t & 15) * 4;                        // col (x4)
    int tr  = t >> 4;                              // 0..31
    #pragma unroll
    for (int j = 0; j < 2; j++) {
        int r = tr + j * 32;
        float4 v = *(const float4*)&inp[(long)(r0 + r) * C + c0 + tc4];
        tile[tc4 + 0][r] = f2b(v.x);
        tile[tc4 + 1][r] = f2b(v.y);
        tile[tc4 + 2][r] = f2b(v.z);
        tile[tc4 + 3][r] = f2b(v.w);
    }
    __syncthreads();
    int oc = t >> 3;                               // 0..63
    int seg = t & 7;                               // 0..7
    bf16x8 o = *(const bf16x8*)&tile[oc][seg * 8];
    *(bf16x8*)&outp[(long)(c0 + oc) * R + r0 + seg * 8] = o;
}

// ---------------- combine: out[t] += outR[pos[2t]] + outR[pos[2t+1]] ----------------
__global__ void comb_k(float* __restrict__ out, const bf16r* __restrict__ outR,
                       const int* __restrict__ pos) {
    int i = blockIdx.x * 256 + threadIdx.x;        // over T_*H_/4
    int t  = i >> 9;                               // H_/4 = 512
    int c4 = i & 511;
    int p0 = pos[2 * t], p1 = pos[2 * t + 1];
    float4 o = ((float4*)out)[i];
    short4v r0 = ((const short4v*)(outR + (long)p0 * H_))[c4];
    short4v r1 = ((const short4v*)(outR + (long)p1 * H_))[c4];
    o.x += b2f((bf16r)r0[0]) + b2f((bf16r)r1[0]);
    o.y += b2f((bf16r)r0[1]) + b2f((bf16r)r1[1]);
    o.z += b2f((bf16r)r0[2]) + b2f((bf16r)r1[2]);
    o.w += b2f((bf16r)r0[3]) + b2f((bf16r)r1[3]);
    ((float4*)out)[i] = o;
}

// =====================================================================
// 8-phase 256-row GEMM body (verified round-2 schedule, runtime routed/gather).
//   BM=256, BK=64, 512 thr (8 waves, 2Mx4N).  BNv=256 (or 128).
//   Phases per K-tile: quadrants (0,0),(0,1),(1,0),(1,1); frag reads issue
//   BEFORE the barrier; stage issue 1 half-tile/phase; counted vmwait<VW>
//   at p0/p1/p3 (readiness one phase ahead; verified by queue induction).
//   LDS swizzle: 16B k-slot u stored at u^(row&7) via pre-swizzled GLOBAL
//   source (linear LDS dest), XOR applied on ds_read.
//   EPI: 0 = paired swiglu bf16 store; 1 = fp32 plain; 2 = bf16 w*acc store.
// =====================================================================

#define PH_READ_A(MH) { _Pragma("unroll") for (int i4 = 0; i4 < 4; i4++) \
                        _Pragma("unroll") for (int kk = 0; kk < 2; kk++) \
                            af[(MH)][i4][kk] = rdA(cur, (MH), i4, kk); }
#define PH_READ_B(NH) { _Pragma("unroll") for (int j2 = 0; j2 < NJ2; j2++) \
                        _Pragma("unroll") for (int kk = 0; kk < 2; kk++) \
                            bfr[(NH)][j2][kk] = rdB(cur, (NH), j2, kk); }
#define PH_MMA(MH, NH) { __builtin_amdgcn_s_setprio(1); \
    _Pragma("unroll") for (int i4 = 0; i4 < 4; i4++) \
    _Pragma("unroll") for (int j2 = 0; j2 < NJ2; j2++) \
    _Pragma("unroll") for (int kk = 0; kk < 2; kk++) \
        acc[(MH)][(NH)][i4][j2] = __builtin_amdgcn_mfma_f32_16x16x32_bf16( \
            af[(MH)][i4][kk], bfr[(NH)][j2][kk], acc[(MH)][(NH)][i4][j2], 0, 0, 0); \
    __builtin_amdgcn_s_setprio(0); }

template<int BNv, int KD, bool PAIRED, int EPI>
__device__ __forceinline__ void g8_body(
    int sub, int nwg, int gM, bool routed, bool gather,
    const bf16r* __restrict__ A,
    const bf16r* __restrict__ Bt, long bstride, int F,
    void* __restrict__ Cv, int ldc,
    const int* __restrict__ off, const int* __restrict__ perm,
    const float* __restrict__ wrow)
{
    constexpr int NJ2 = BNv / 128;           // N frags per wave per quadrant (2 or 1)
    constexpr int LB  = NJ2;                 // gld16 per thread per B half
    constexpr int BHE = BNv * 32;            // B half elements
    constexpr int NT  = KD / 64;
    constexpr int VW  = 4 + 2 * LB;          // steady-state wait count
    static_assert(!PAIRED || NJ2 == 2, "paired swiglu needs BN=256");
    static_assert(NT >= 4 && (NT & 1) == 0, "even K-tile count >= 4");

    extern __shared__ __align__(16) char smem[];
    bf16r* lA = (bf16r*)smem;                // [buf][half] x 8192 elems
    bf16r* lB = (bf16r*)(smem + 65536);

    // bijective XCD-aware remap (nwg here always %8==0), M-fastest
    int q8 = nwg >> 3, xc = sub & 7, o8 = sub >> 3;
    int wgid = xc * q8 + o8;
    int mt = wgid % gM, nt = wgid / gM;
    const int r0 = mt * 256;
    int e = 0;
    if (routed) {
        if (r0 >= off[E_]) return;           // uniform: before any barrier
        while (e + 1 < E_ && off[e + 1] <= r0) e++;
    }
    const bf16r* Bte = routed ? Bt + (long)e * bstride : Bt;

    const int tid  = threadIdx.x;
    const int lane = tid & 63;
    const int wave = tid >> 6;
    const int wm = wave >> 2, wn = wave & 3;
    const int ml = lane & 15, kg = lane >> 4;
    const int srw  = lane >> 3;                       // staged row within 8-row group
    const int ksrc = ((lane & 7) ^ srw) * 8;          // pre-swizzled global k offset

    // ---- staging pointers (k0 added per tile) ----
    const bf16r* pA[2][2];
    #pragma unroll
    for (int h = 0; h < 2; h++)
        #pragma unroll
        for (int l = 0; l < 2; l++) {
            int gr = r0 + h * 128 + (wave + 8 * l) * 8 + srw;
            long rw = gr;
            if (gather) { int tk = perm[gr]; rw = (tk < 0) ? 0 : tk; }
            pA[h][l] = A + rw * (long)KD + ksrc;
        }
    const bf16r* pB[2][LB];
    #pragma unroll
    for (int nh = 0; nh < 2; nh++)
        #pragma unroll
        for (int l = 0; l < LB; l++) {
            int lr = (wave + 8 * l) * 8 + srw;        // local B row in half
            long gr;
            if (PAIRED) {
                int wn_ = lr >> 5, j2_ = (lr >> 4) & 1, ml_ = lr & 15;
                gr = (long)(nt * 128 + nh * 64 + wn_ * 16 + ml_) + (j2_ ? (long)F : 0L);
            } else if (NJ2 == 2) gr = (long)(nt * 256 + nh * 128 + lr);
            else                 gr = (long)(nt * 128 + nh * 64  + lr);
            pB[nh][l] = Bte + gr * (long)KD + ksrc;
        }

    auto stgA = [&](int b, int h, int kp) {
        char* d = smem + ((b * 2 + h) << 14) + (wave << 10);
        gld16(pA[h][0] + kp, d);
        gld16(pA[h][1] + kp, d + 8192);
    };
    auto stgB = [&](int b, int nh, int kp) {
        char* d = smem + 65536 + (b * 2 + nh) * (BHE * 2) + (wave << 10);
        gld16(pB[nh][0] + kp, d);
        if constexpr (LB == 2) gld16(pB[nh][1] + kp, d + 8192);
    };
    // swizzled reads: logical 16B k-unit u lives at u^(row&7)
    auto rdA = [&](int b, int mh, int i4, int kk) -> bf16x8 {
        int row = wm * 64 + i4 * 16 + ml;
        int u = kk * 4 + kg;
        int ee = ((b * 2 + mh) << 13) + row * 64 + ((u ^ (row & 7)) << 3);
        return *(const bf16x8*)&lA[ee];
    };
    auto rdB = [&](int b, int nh, int j2, int kk) -> bf16x8 {
        int rb = (NJ2 == 2) ? (wn * 32 + j2 * 16 + ml) : (wn * 16 + ml);
        int u = kk * 4 + kg;
        int ee = (b * 2 + nh) * BHE + rb * 64 + ((u ^ (rb & 7)) << 3);
        return *(const bf16x8*)&lB[ee];
    };

    f32x4 acc[2][2][4][NJ2];
    #pragma unroll
    for (int a0 = 0; a0 < 2; a0++)
        #pragma unroll
        for (int b0 = 0; b0 < 2; b0++)
            #pragma unroll
            for (int i = 0; i < 4; i++)
                #pragma unroll
                for (int j = 0; j < NJ2; j++)
                    acc[a0][b0][i][j] = f32x4{0.f, 0.f, 0.f, 0.f};

    bf16x8 af[2][4][2], bfr[2][NJ2][2];

    // prologue: tile0 all 4 halves + tile1 A0,B0; drain tile0 only
    vmwait<0>();
    stgA(0, 0, 0); stgB(0, 0, 0); stgB(0, 1, 0); stgA(0, 1, 0);
    stgA(1, 0, 64); stgB(1, 0, 64);
    vmwait<LB + 2>(); barrier_raw();

    #pragma unroll 2
    for (int t = 0; t < NT; t++) {
        const int cur = t & 1, nxt = cur ^ 1;
        const int k1 = ((t + 1 < NT) ? (t + 1) : (NT - 1)) * 64;  // clamped: uniform counts
        const int k2 = ((t + 2 < NT) ? (t + 2) : (NT - 1)) * 64;
        // ---- phase 0: quadrant (0,0) ----
        PH_READ_A(0); PH_READ_B(0);     // ready since end of (t-1,p3)
        stgB(nxt, 1, k1);               // B1(t+1)
        vmwait<VW>();                   // completes B1(t)
        barrier_raw();
        PH_MMA(0, 0);
        barrier_raw();
        // ---- phase 1: (0,1) ----
        PH_READ_B(1);                   // B1(t): ready since p0's wait+barrier
        stgA(nxt, 1, k1);               // A1(t+1)
        vmwait<VW>();                   // completes A1(t)
        barrier_raw();
        PH_MMA(0, 1);
        barrier_raw();
        // ---- phase 2: (1,0) ----
        PH_READ_A(1);                   // A1(t): ready since p1's wait+barrier
        stgA(cur, 0, k2);               // A0(t+2) (same-parity buffer)
        barrier_raw();
        PH_MMA(1, 0);
        barrier_raw();
        // ---- phase 3: (1,1) ----
        stgB(cur, 0, k2);               // B0(t+2)
        vmwait<VW>();                   // completes A0(t+1), B0(t+1)
        barrier_raw();
        PH_MMA(1, 1);
        barrier_raw();
    }
    vmwait<0>();                        // drain LDS-DMA before wave exit

    // ---------------- epilogue: D row = kg*4+rr, col = ml (verified m89) ----------------
    const long colbase = (long)nt * (PAIRED ? 128 : BNv);
    #pragma unroll
    for (int mh = 0; mh < 2; mh++)
        #pragma unroll
        for (int i4 = 0; i4 < 4; i4++)
            #pragma unroll
            for (int rr = 0; rr < 4; rr++) {
                long row = (long)r0 + mh * 128 + wm * 64 + i4 * 16 + kg * 4 + rr;
                if constexpr (PAIRED) {
                    bf16r* ap = (bf16r*)Cv + row * (long)ldc + colbase;
                    #pragma unroll
                    for (int nh = 0; nh < 2; nh++) {
                        float g = acc[mh][nh][i4][0][rr];
                        float u = acc[mh][nh][i4][1][rr];
                        float s = g / (1.0f + __expf(-g));
                        ap[nh * 64 + wn * 16 + ml] = f2b(s * u);
                    }
                } else if constexpr (EPI == 1) {
                    float* cp = (float*)Cv + row * (long)ldc + colbase;
                    #pragma unroll
                    for (int nh = 0; nh < 2; nh++)
                        #pragma unroll
                        for (int j2 = 0; j2 < NJ2; j2++)
                            cp[nh * (BNv / 2) + wn * (BNv / 8) + j2 * 16 + ml] =
                                acc[mh][nh][i4][j2][rr];
                } else {  // EPI == 2: bf16 w*acc, row-contiguous (combined later)
                    int tok = perm[row];
                    if (tok >= 0) {
                        float w = wrow[row];
                        bf16r* cp = (bf16r*)Cv + row * (long)ldc + colbase;
                        #pragma unroll
                        for (int nh = 0; nh < 2; nh++)
                            #pragma unroll
                            for (int j2 = 0; j2 < NJ2; j2++)
                                cp[nh * (BNv / 2) + wn * (BNv / 8) + j2 * 16 + ml] =
                                    f2b(w * acc[mh][nh][i4][j2][rr]);
                    }
                }
            }
}

#undef PH_READ_A
#undef PH_READ_B
#undef PH_MMA

// ---------------- merged GEMM1 dispatch: shared (352) + routed (440) ----------------
__global__ __launch_bounds__(512, 2)
void g1m_k(const bf16r* __restrict__ xb,
           const bf16r* __restrict__ Ws1t, bf16r* __restrict__ actS,
           const bf16r* __restrict__ W1t,  bf16r* __restrict__ actR,
           const int* __restrict__ route)
{
    const int* off  = route + 32;
    const int* perm = route + 64;
    int orig = blockIdx.x;
    bool rt = orig >= NS1;
    int sub  = rt ? orig - NS1 : orig;
    int nwg  = rt ? NR1 : NS1;
    int gM   = rt ? MAXR / 256 : T_ / 256;
    const bf16r* B = rt ? W1t : Ws1t;
    long bs  = rt ? (long)I2 * H_ : 0;
    int F    = rt ? IH : SIH;
    bf16r* C = rt ? actR : actS;
    int ldc  = rt ? IH : SIH;
    g8_body<256, 2048, true, 0>(sub, nwg, gM, rt, rt, xb, B, bs, F, C, ldc,
                                off, perm, nullptr);
}

// ---------------- merged GEMM2 dispatch: shared (256, fp32) + routed (320, bf16 w*acc) ----
__global__ __launch_bounds__(512, 2)
void g2m_k(const bf16r* __restrict__ actS, const bf16r* __restrict__ Ws2t,
           float* __restrict__ out,
           const bf16r* __restrict__ actR, const bf16r* __restrict__ W2t,
           bf16r* __restrict__ outR,
           const int* __restrict__ route)
{
    const int* off  = route + 32;
    const int* perm = route + 64;
    const float* wrow = (const float*)(route + 64 + MAXR);
    int orig = blockIdx.x;
    if (orig < NS2) {
        g8_body<128, 2816, false, 1>(orig, NS2, T_ / 256, false, false,
                                     actS, Ws2t, 0, 0, out, H_, off, perm, nullptr);
    } else {
        g8_body<256, 1408, false, 2>(orig - NS2, NR2, MAXR / 256, true, false,
                                     actR, W2t, (long)H_ * IH, 0, outR, H_, off, perm, wrow);
    }
}

// ---------------- launcher ----------------
extern "C" void kernel_launch(void* const* d_in, const int* in_sizes, int n_in,
                              void* d_out, int out_size, void* d_ws, size_t ws_size,
                              hipStream_t stream)
{
    const float* x   = (const float*)d_in[0];
    const float* tw  = (const float*)d_in[1];
    const float* W1  = (const float*)d_in[2];
    const float* W2  = (const float*)d_in[3];
    const float* Ws1 = (const float*)d_in[4];
    const float* Ws2 = (const float*)d_in[5];
    const int*   tix = (const int*)d_in[6];
    float* out = (float*)d_out;

    char* ws    = (char*)d_ws;
    int*  route = (int*)ws;
    const int* pos = route + 64 + 2 * MAXR;

    bf16r* xb   = (bf16r*)(ws + (1u << 20));
    bf16r* W1t  = xb   + (size_t)T_ * H_;
    bf16r* W2t  = W1t  + (size_t)E_ * I2 * H_;
    bf16r* Ws1t = W2t  + (size_t)E_ * H_ * IH;
    bf16r* Ws2t = Ws1t + (size_t)SI2 * H_;
    bf16r* actS = Ws2t + (size_t)H_ * SIH;
    bf16r* actR = actS + (size_t)T_ * SIH;      // total ~243 MB
    // outR [MAXR][H] bf16 (40 MB) aliases W1t (92 MB), dead after merged GEMM1
    bf16r* outR = W1t;

    static bool attr_done = false;
    if (!attr_done) {
        hipFuncSetAttribute(reinterpret_cast<const void*>(&g1m_k),
                            hipFuncAttributeMaxDynamicSharedMemorySize, 131072);
        hipFuncSetAttribute(reinterpret_cast<const void*>(&g2m_k),
                            hipFuncAttributeMaxDynamicSharedMemorySize, 131072);
        attr_done = true;
    }

    // routing (single block)
    route_k<<<1, 256, 0, stream>>>(tix, tw, route);

    // converts: x flat; weights transpose-convert to [N][K] bf16
    cvt_k<<<(T_ * H_ / 4 + 255) / 256, 256, 0, stream>>>(x, xb, T_ * H_ / 4);
    tconv2_k<<<dim3(SI2 / 64, H_ / 64, 1), 512, 0, stream>>>(Ws1, Ws1t, H_, SI2, 0, 0);
    tconv2_k<<<dim3(H_ / 64, SIH / 64, 1), 512, 0, stream>>>(Ws2, Ws2t, SIH, H_, 0, 0);
    tconv2_k<<<dim3(I2 / 64, H_ / 64, E_), 512, 0, stream>>>(W1, W1t, H_, I2,
                                                             (long)H_ * I2, (long)I2 * H_);
    tconv2_k<<<dim3(H_ / 64, IH / 64, E_), 512, 0, stream>>>(W2, W2t, IH, H_,
                                                             (long)IH * H_, (long)H_ * IH);

    // merged GEMM1: shared (-> actS) + routed (-> actR), swiglu fused
    g1m_k<<<dim3(NS1 + NR1), dim3(512), 131072, stream>>>(xb, Ws1t, actS, W1t, actR, route);
    // merged GEMM2: shared (-> out fp32) + routed (-> outR bf16 w*acc)
    g2m_k<<<dim3(NS2 + NR2), dim3(512), 131072, stream>>>(actS, Ws2t, out, actR, W2t, outR, route);
    // combine: out[t] += outR[pos0] + outR[pos1]
    comb_k<<<T_ * H_ / 4 / 256, 256, 0, stream>>>(out, outR, pos);
}